// Round 2
// baseline (707.549 us; speedup 1.0000x reference)
//
#include <hip/hip_runtime.h>
#include <hip/hip_bf16.h>

// ---------------------------------------------------------------------------
// SRCNN: bicubic x8 upscale -> conv9x9(4->64)+ReLU -> conv1x1(64->32)+ReLU
//        -> conv5x5(32->4).  Input/output dtype detected at runtime (fp32 vs
//        bf16) via a device-side probe; all compute in fp32.
// Workspace layout (floats unless noted):
//   wf[0      .. 20736)  w1t  [ic][ky][kx][oc]   (4*9*9*64, tap-major)
//   wf[20736  .. 20800)  b1f  [64]
//   wf[20800  .. 22848)  w2t  [oc1][oc2]         (64*32)
//   wf[22848  .. 22880)  b2f  [32]
//   wf[22880  .. 26080)  w3t  [ic][ky][kx][oc]   (32*5*5*4)
//   wf[26080  .. 26084)  b3f  [4]
//   wf[26100]            dtype flag (1 = bf16, 0 = fp32), written by k_probe
//   up = wf + 26112      fp32 NCHW [16][4][256][256]   (4,194,304 floats)
//   h2 = (bf16*)(up + 4194304)  bf16 NCHW [16][32][256][256]
// Total ws: ~84 MB.
// ---------------------------------------------------------------------------

#define W1T_OFF 0
#define B1_OFF  20736
#define W2T_OFF 20800
#define B2_OFF  22848
#define W3T_OFF 22880
#define B3_OFF  26080
#define WF_TOTAL 26084
#define FLAG_OFF 26100
#define WF_PAD   26112
#define UP_ELEMS 4194304   // 16*4*256*256

__device__ __forceinline__ float load_in(const void* p, int i, int isbf16) {
  if (isbf16) {
    unsigned short h = ((const unsigned short*)p)[i];
    unsigned int u = ((unsigned int)h) << 16;
    return __uint_as_float(u);
  }
  return ((const float*)p)[i];
}

// ---------------- K_probe: detect input dtype ------------------------------
// Even halfwords of a bf16 tensor are bf16 elements (exponent in a narrow
// band for ~N(0,1) data).  Even halfwords of an fp32 tensor are low mantissa
// bits (uniform).  Count exponent-in-band hits over 512 samples.
__global__ __launch_bounds__(256) void k_probe(const unsigned short* __restrict__ xr,
                                               int* __restrict__ flag) {
  __shared__ int s[256];
  int tid = threadIdx.x;
  int cnt = 0;
  for (int i = tid; i < 512; i += 256) {
    unsigned short h = xr[2 * i];          // bytes 0..2045 only (safe for bf16 buf)
    int e = (h >> 7) & 0xFF;
    if (e >= 110 && e <= 135) cnt++;
  }
  s[tid] = cnt;
  __syncthreads();
  if (tid == 0) {
    int t = 0;
    for (int i = 0; i < 256; i++) t += s[i];
    flag[0] = (t >= 256) ? 1 : 0;
  }
}

// ---------------- K0: convert + transpose weights to fp32 ------------------
__global__ __launch_bounds__(256) void k_cvt_weights(
    const void* __restrict__ w1, const void* __restrict__ b1,
    const void* __restrict__ w2, const void* __restrict__ b2,
    const void* __restrict__ w3, const void* __restrict__ b3,
    float* __restrict__ wf, const int* __restrict__ flag) {
  int i = blockIdx.x * 256 + threadIdx.x;
  if (i >= WF_TOTAL) return;
  const int f = flag[0];
  float v;
  if (i < B1_OFF) {                       // w1t: ((ic*9+ky)*9+kx)*64+oc
    int j = i;
    int oc = j & 63;
    int r  = j >> 6;            // (ic*9+ky)*9+kx, in [0,324)
    int ic = r / 81;
    int r2 = r % 81;
    int ky = r2 / 9, kx = r2 % 9;
    v = load_in(w1, ((oc * 4 + ic) * 9 + ky) * 9 + kx, f);
  } else if (i < W2T_OFF) {
    v = load_in(b1, i - B1_OFF, f);
  } else if (i < B2_OFF) {                // w2t: oc1*32+oc2  <- w2[oc2*64+oc1]
    int j = i - W2T_OFF;
    int oc1 = j >> 5, oc2 = j & 31;
    v = load_in(w2, oc2 * 64 + oc1, f);
  } else if (i < W3T_OFF) {
    v = load_in(b2, i - B2_OFF, f);
  } else if (i < B3_OFF) {                // w3t: ((ic*5+ky)*5+kx)*4+oc
    int j = i - W3T_OFF;
    int oc = j & 3;
    int r  = j >> 2;            // (ic*5+ky)*5+kx in [0,800)
    int ic = r / 25;
    int r2 = r % 25;
    int ky = r2 / 5, kx = r2 % 5;
    v = load_in(w3, ((oc * 32 + ic) * 5 + ky) * 5 + kx, f);
  } else {
    v = load_in(b3, i - B3_OFF, f);
  }
  wf[i] = v;
}

// ---------------- K1: bicubic x8 upscale (NHWC -> NCHW fp32) ---------------
__device__ __forceinline__ float cubicw(float d) {
  const float Ac = -0.75f;
  d = fabsf(d);
  float d2 = d * d, d3 = d2 * d;
  if (d <= 1.f) return (Ac + 2.f) * d3 - (Ac + 3.f) * d2 + 1.f;
  if (d < 2.f)  return Ac * d3 - 5.f * Ac * d2 + 8.f * Ac * d - 4.f * Ac;
  return 0.f;
}

__global__ __launch_bounds__(256) void k_upscale(
    const void* __restrict__ x, float* __restrict__ up,
    const int* __restrict__ flag) {
  const int f = flag[0];
  int idx = blockIdx.x * 256 + threadIdx.x;   // NCHW flat: ((b*4+c)*256+y)*256+x
  int xo = idx & 255;
  int yo = (idx >> 8) & 255;
  int c  = (idx >> 16) & 3;
  int b  = idx >> 18;
  float sx = (xo + 0.5f) * 0.125f - 0.5f;
  float sy = (yo + 0.5f) * 0.125f - 0.5f;
  int bx = (int)floorf(sx), by = (int)floorf(sy);
  float tx = sx - (float)bx, ty = sy - (float)by;
  float wx[4], wy[4];
#pragma unroll
  for (int a = 0; a < 4; a++) {
    wx[a] = cubicw(tx - (float)(a - 1));
    wy[a] = cubicw(ty - (float)(a - 1));
  }
  float acc = 0.f;
#pragma unroll
  for (int a = 0; a < 4; a++) {
    int iy = min(max(by + a - 1, 0), 31);
    float r = 0.f;
#pragma unroll
    for (int bb = 0; bb < 4; bb++) {
      int ix = min(max(bx + bb - 1, 0), 31);
      r += wx[bb] * load_in(x, ((b * 32 + iy) * 32 + ix) * 4 + c, f);
    }
    acc += wy[a] * r;
  }
  up[idx] = acc;
}

// ---------------- K2: fused conv9x9(4->64)+ReLU -> conv1x1(64->32)+ReLU ----
// block = 256 threads = 16x16 pixel tile; grid = (16,16,B)
__global__ __launch_bounds__(256) void k_conv12(
    const float* __restrict__ up, const float* __restrict__ wf,
    __hip_bfloat16* __restrict__ h2) {
  __shared__ float patch[4 * 24 * 24];   // 9216 B
  const int b  = blockIdx.z;
  const int x0 = blockIdx.x * 16, y0 = blockIdx.y * 16;
  const int tid = threadIdx.x;

  // stage 24x24x4 input patch (zero padding, pad=4)
  for (int e = tid; e < 4 * 24 * 24; e += 256) {
    int ic = e / 576;
    int r  = e % 576;
    int py = r / 24, px = r % 24;
    int gy = y0 + py - 4, gx = x0 + px - 4;
    float v = 0.f;
    if (gy >= 0 && gy < 256 && gx >= 0 && gx < 256)
      v = up[((b * 4 + ic) * 256 + gy) * 256 + gx];
    patch[e] = v;
  }
  __syncthreads();

  const int tx = tid & 15, ty = tid >> 4;
  const float* __restrict__ w1t = wf + W1T_OFF;
  const float* __restrict__ b1f = wf + B1_OFF;
  const float* __restrict__ w2t = wf + W2T_OFF;
  const float* __restrict__ b2f = wf + B2_OFF;

  float acc2[32];
#pragma unroll
  for (int k = 0; k < 32; k++) acc2[k] = b2f[k];

  for (int c0 = 0; c0 < 64; c0 += 16) {
    float acc[16];
#pragma unroll
    for (int j = 0; j < 16; j++) acc[j] = b1f[c0 + j];
#pragma unroll
    for (int ic = 0; ic < 4; ic++) {
      for (int ky = 0; ky < 9; ky++) {
        float row[9];
#pragma unroll
        for (int kx = 0; kx < 9; kx++)
          row[kx] = patch[ic * 576 + (ty + ky) * 24 + tx + kx];
#pragma unroll
        for (int kx = 0; kx < 9; kx++) {
          const float* wrow = w1t + ((ic * 9 + ky) * 9 + kx) * 64 + c0;
#pragma unroll
          for (int j = 0; j < 16; j++)
            acc[j] = fmaf(row[kx], wrow[j], acc[j]);
        }
      }
    }
#pragma unroll
    for (int j = 0; j < 16; j++) {
      float a = fmaxf(acc[j], 0.f);               // ReLU after conv1
      const float* w2row = w2t + (c0 + j) * 32;
#pragma unroll
      for (int k = 0; k < 32; k++)
        acc2[k] = fmaf(a, w2row[k], acc2[k]);
    }
  }

  const int y = y0 + ty, xx = x0 + tx;
#pragma unroll
  for (int k = 0; k < 32; k++) {
    float a = fmaxf(acc2[k], 0.f);                // ReLU after conv2
    h2[((b * 32 + k) * 256 + y) * 256 + xx] = __float2bfloat16(a);
  }
}

// ---------------- K3: conv5x5(32->4), write NHWC out (dtype per flag) ------
// block = 256 threads = 16x16 pixel tile; grid = (16,16,B)
__global__ __launch_bounds__(256) void k_conv3(
    const __hip_bfloat16* __restrict__ h2, const float* __restrict__ wf,
    void* __restrict__ out, const int* __restrict__ flag) {
  __shared__ float patch[32 * 20 * 20];  // 51200 B
  const int b  = blockIdx.z;
  const int x0 = blockIdx.x * 16, y0 = blockIdx.y * 16;
  const int tid = threadIdx.x;

  for (int e = tid; e < 32 * 20 * 20; e += 256) {
    int ic = e / 400;
    int r  = e % 400;
    int py = r / 20, px = r % 20;
    int gy = y0 + py - 2, gx = x0 + px - 2;
    float v = 0.f;
    if (gy >= 0 && gy < 256 && gx >= 0 && gx < 256)
      v = __bfloat162float(h2[((b * 32 + ic) * 256 + gy) * 256 + gx]);
    patch[e] = v;
  }
  __syncthreads();

  const int tx = tid & 15, ty = tid >> 4;
  const float* __restrict__ w3t = wf + W3T_OFF;
  const float* __restrict__ b3f = wf + B3_OFF;

  float acc[4];
#pragma unroll
  for (int oc = 0; oc < 4; oc++) acc[oc] = b3f[oc];

  for (int ic = 0; ic < 32; ic++) {
#pragma unroll
    for (int ky = 0; ky < 5; ky++) {
      float row[5];
#pragma unroll
      for (int kx = 0; kx < 5; kx++)
        row[kx] = patch[(ic * 20 + ty + ky) * 20 + tx + kx];
#pragma unroll
      for (int kx = 0; kx < 5; kx++) {
        const float* w = w3t + ((ic * 5 + ky) * 5 + kx) * 4;
#pragma unroll
        for (int oc = 0; oc < 4; oc++)
          acc[oc] = fmaf(row[kx], w[oc], acc[oc]);
      }
    }
  }

  const int y = y0 + ty, xx = x0 + tx;
  const int base = (((b * 256 + y) * 256 + xx) << 2);
  if (flag[0]) {
    __hip_bfloat16* o = (__hip_bfloat16*)out + base;
#pragma unroll
    for (int oc = 0; oc < 4; oc++) o[oc] = __float2bfloat16(acc[oc]);
  } else {
    float* o = (float*)out + base;
#pragma unroll
    for (int oc = 0; oc < 4; oc++) o[oc] = acc[oc];
  }
}

// ---------------------------------------------------------------------------
extern "C" void kernel_launch(void* const* d_in, const int* in_sizes, int n_in,
                              void* d_out, int out_size, void* d_ws, size_t ws_size,
                              hipStream_t stream) {
  const void* x  = d_in[0];
  const void* w1 = d_in[1];
  const void* b1 = d_in[2];
  const void* w2 = d_in[3];
  const void* b2 = d_in[4];
  const void* w3 = d_in[5];
  const void* b3 = d_in[6];

  float* wf = (float*)d_ws;
  int* flag = (int*)(wf + FLAG_OFF);
  float* up = wf + WF_PAD;
  __hip_bfloat16* h2 = (__hip_bfloat16*)(up + UP_ELEMS);

  // K_probe: detect fp32 vs bf16 input encoding
  k_probe<<<1, 256, 0, stream>>>((const unsigned short*)x, flag);
  // K0: weights -> fp32 (transposed tap-major)
  k_cvt_weights<<<(WF_TOTAL + 255) / 256, 256, 0, stream>>>(w1, b1, w2, b2, w3, b3, wf, flag);
  // K1: bicubic upscale
  k_upscale<<<UP_ELEMS / 256, 256, 0, stream>>>(x, up, flag);
  // K2: fused conv1+relu+conv2+relu
  k_conv12<<<dim3(16, 16, 16), 256, 0, stream>>>(up, wf, h2);
  // K3: conv3 + NHWC output
  k_conv3<<<dim3(16, 16, 16), 256, 0, stream>>>(h2, wf, d_out, flag);
}

// Round 3
// 337.376 us; speedup vs baseline: 2.0972x; 2.0972x over previous
//
#include <hip/hip_runtime.h>
#include <hip/hip_bf16.h>

typedef unsigned short ushort_t;
typedef __attribute__((ext_vector_type(8))) short v8s;   // 8 bf16 = 4 VGPR (MFMA A/B)
typedef __attribute__((ext_vector_type(4))) float v4f;   // MFMA C/D

// ---------------------------------------------------------------------------
// ws layout:
//   bytes [0, 73728)           : pack1 — conv1 B-fragments bf16 [ks 18][nt 4][lane 64][8]
//   floats (base FP region):
#define PACK1_USHORTS 36864
#define FP_BASE   18432              // float index = 73728/4
#define B1F_OFF   (FP_BASE + 0)      // 64 floats
#define W2T_OFF   (FP_BASE + 64)     // 2048 floats  [oc1][oc2]
#define B2F_OFF   (FP_BASE + 2112)   // 32
#define W3T_OFF   (FP_BASE + 2144)   // 3200  [ic][ky][kx][oc]
#define B3F_OFF   (FP_BASE + 5344)   // 4
#define FLAG_OFF  (FP_BASE + 5352)   // int (1 = bf16 inputs, 0 = fp32)
#define UP_OFF    (FP_BASE + 5376)   // fp32 NHWC [16][256][256][4]
#define UP_ELEMS  4194304
#define H2_OFF_F  (UP_OFF + UP_ELEMS) // h2 bf16 NCHW [16][32][256][256] starts here
// ---------------------------------------------------------------------------

__device__ __forceinline__ ushort_t f2us(float v) {
  __hip_bfloat16 h = __float2bfloat16(v);
  return *reinterpret_cast<ushort_t*>(&h);
}
__device__ __forceinline__ float us2f(unsigned int u) {  // u = bf16 bits in low 16
  return __uint_as_float(u << 16);
}

__device__ __forceinline__ float load_in(const void* p, int i, int isbf16) {
  if (isbf16) {
    unsigned short h = ((const unsigned short*)p)[i];
    return __uint_as_float(((unsigned int)h) << 16);
  }
  return ((const float*)p)[i];
}
__device__ __forceinline__ float4 load_in4(const void* p, int i4, int isbf16) {
  // i4 = element index, multiple of 4
  if (isbf16) {
    unsigned long long q = *(const unsigned long long*)((const unsigned short*)p + i4);
    return make_float4(us2f((unsigned int)(q & 0xffff)),
                       us2f((unsigned int)((q >> 16) & 0xffff)),
                       us2f((unsigned int)((q >> 32) & 0xffff)),
                       us2f((unsigned int)((q >> 48) & 0xffff)));
  }
  return *(const float4*)((const float*)p + i4);
}

// ---------------- K_probe: detect input dtype ------------------------------
__global__ __launch_bounds__(256) void k_probe(const unsigned short* __restrict__ xr,
                                               int* __restrict__ flag) {
  __shared__ int s[256];
  int tid = threadIdx.x;
  int cnt = 0;
  for (int i = tid; i < 512; i += 256) {
    unsigned short h = xr[2 * i];
    int e = (h >> 7) & 0xFF;
    if (e >= 110 && e <= 135) cnt++;
  }
  s[tid] = cnt;
  __syncthreads();
  if (tid == 0) {
    int t = 0;
    for (int i = 0; i < 256; i++) t += s[i];
    flag[0] = (t >= 256) ? 1 : 0;
  }
}

// ---------------- K_cvt: weights -> pack1 (bf16 B-frags) + fp32 tables -----
__global__ __launch_bounds__(256) void k_cvt(
    const void* __restrict__ w1, const void* __restrict__ b1,
    const void* __restrict__ w2, const void* __restrict__ b2,
    const void* __restrict__ w3, const void* __restrict__ b3,
    ushort_t* __restrict__ pack1, float* __restrict__ wf,
    const int* __restrict__ flag) {
  int i = blockIdx.x * 256 + threadIdx.x;
  const int f = flag[0];
  if (i < PACK1_USHORTS) {
    // [ks][nt][lane][j]: k = ks*32 + quad*8 + j; n = nt*16 + (lane&15)
    int j  = i & 7;
    int l  = (i >> 3) & 63;
    int nt = (i >> 9) & 3;
    int ks = i >> 11;
    int k  = ks * 32 + ((l >> 4) & 3) * 8 + j;
    int oc = nt * 16 + (l & 15);
    int ky = k >> 6, kx = (k >> 2) & 15, ic = k & 3;   // k = ky*64 + kx*4 + ic
    float v = 0.f;
    if (kx < 9) v = load_in(w1, ((oc * 4 + ic) * 9 + ky) * 9 + kx, f);
    pack1[i] = f2us(v);
    return;
  }
  int t = i - PACK1_USHORTS;
  if (t < 64) {
    wf[B1F_OFF + t] = load_in(b1, t, f);
  } else if (t < 2112) {
    int j = t - 64; int o1 = j >> 5, o2 = j & 31;
    wf[W2T_OFF + j] = load_in(w2, o2 * 64 + o1, f);     // w2t[oc1][oc2]
  } else if (t < 2144) {
    wf[B2F_OFF + (t - 2112)] = load_in(b2, t - 2112, f);
  } else if (t < 5344) {
    int j = t - 2144;
    int oc = j & 3, r = j >> 2;
    int ic = r / 25, r2 = r % 25, ky = r2 / 5, kx = r2 % 5;
    wf[W3T_OFF + j] = load_in(w3, ((oc * 32 + ic) * 5 + ky) * 5 + kx, f);
  } else if (t < 5348) {
    wf[B3F_OFF + (t - 5344)] = load_in(b3, t - 5344, f);
  }
}

// ---------------- K1: bicubic x8 upscale -> fp32 NHWC ----------------------
__device__ __forceinline__ float cubicw(float d) {
  const float Ac = -0.75f;
  d = fabsf(d);
  float d2 = d * d, d3 = d2 * d;
  if (d <= 1.f) return (Ac + 2.f) * d3 - (Ac + 3.f) * d2 + 1.f;
  if (d < 2.f)  return Ac * d3 - 5.f * Ac * d2 + 8.f * Ac * d - 4.f * Ac;
  return 0.f;
}

__global__ __launch_bounds__(256) void k_upscale(
    const void* __restrict__ x, float* __restrict__ up,
    const int* __restrict__ flag) {
  const int f = flag[0];
  int n = blockIdx.x * 256 + threadIdx.x;   // (b,y,x) position, all 4 channels
  int xo = n & 255, yo = (n >> 8) & 255, b = n >> 16;
  float sx = (xo + 0.5f) * 0.125f - 0.5f;
  float sy = (yo + 0.5f) * 0.125f - 0.5f;
  int bx = (int)floorf(sx), by = (int)floorf(sy);
  float tx = sx - (float)bx, ty = sy - (float)by;
  float wx[4], wy[4];
#pragma unroll
  for (int a = 0; a < 4; a++) {
    wx[a] = cubicw(tx - (float)(a - 1));
    wy[a] = cubicw(ty - (float)(a - 1));
  }
  float ax = 0.f, ay = 0.f, az = 0.f, aw = 0.f;
#pragma unroll
  for (int a = 0; a < 4; a++) {
    int iy = min(max(by + a - 1, 0), 31);
    float rx = 0.f, ry = 0.f, rz = 0.f, rw = 0.f;
#pragma unroll
    for (int bb = 0; bb < 4; bb++) {
      int ix = min(max(bx + bb - 1, 0), 31);
      float4 pv = load_in4(x, ((b * 32 + iy) * 32 + ix) * 4, f);
      rx = fmaf(wx[bb], pv.x, rx); ry = fmaf(wx[bb], pv.y, ry);
      rz = fmaf(wx[bb], pv.z, rz); rw = fmaf(wx[bb], pv.w, rw);
    }
    ax = fmaf(wy[a], rx, ax); ay = fmaf(wy[a], ry, ay);
    az = fmaf(wy[a], rz, az); aw = fmaf(wy[a], rw, aw);
  }
  *(float4*)(up + n * 4) = make_float4(ax, ay, az, aw);
}

// ---------------- K2: MFMA conv9x9(4->64)+ReLU, fused VALU conv1x1+ReLU ----
// tile 32x8 pixels (M=256), grid (8,32,16), 256 threads = 4 waves.
// Wave w owns mtiles 4w..4w+3 (mt -> py = mt>>1, px-half = (mt&1)*16), all 4 ntiles.
__global__ __launch_bounds__(256) void k_conv12(
    const float* __restrict__ up, const ushort_t* __restrict__ pack1,
    const float* __restrict__ wf, ushort_t* __restrict__ h2) {
  __shared__ ushort_t patchA[16 * 48 * 4];   // [y][x][ic] bf16, 6144 B
  __shared__ ushort_t h1[256 * 66];          // [pixel][oc] stride 66, 33792 B
  const int b  = blockIdx.z;
  const int x0 = blockIdx.x * 32, y0 = blockIdx.y * 8;
  const int tid = threadIdx.x;

  // stage 16x48 patch positions (pad=4 left/top; x 40..47 is kx-pad slack, zeroed OOB)
#pragma unroll
  for (int i = 0; i < 3; ++i) {
    int e = tid + i * 256;                  // 0..767
    int yy = e / 48, xx = e % 48;
    int gy = y0 + yy - 4, gx = x0 + xx - 4;
    float4 v = make_float4(0.f, 0.f, 0.f, 0.f);
    if (gy >= 0 && gy < 256 && gx >= 0 && gx < 256)
      v = *(const float4*)(up + (((b * 256 + gy) * 256 + gx) << 2));
    unsigned long long q =
        (unsigned long long)f2us(v.x) |
        ((unsigned long long)f2us(v.y) << 16) |
        ((unsigned long long)f2us(v.z) << 32) |
        ((unsigned long long)f2us(v.w) << 48);
    *(unsigned long long*)(patchA + e * 4) = q;
  }
  __syncthreads();

  const int lane = tid & 63, wave = tid >> 6;
  const int quad = lane >> 4, lc = lane & 15;
  int py_[4], pxh_[4];
#pragma unroll
  for (int i = 0; i < 4; ++i) {
    int mt = wave * 4 + i;
    py_[i] = mt >> 1; pxh_[i] = (mt & 1) << 4;
  }
  v4f acc[4][4];
#pragma unroll
  for (int i = 0; i < 4; ++i)
#pragma unroll
    for (int nt = 0; nt < 4; ++nt) acc[i][nt] = (v4f){0.f, 0.f, 0.f, 0.f};

  const v8s* __restrict__ Bp = (const v8s*)pack1;
  for (int ks = 0; ks < 18; ++ks) {
    v8s Bf[4];
#pragma unroll
    for (int nt = 0; nt < 4; ++nt) Bf[nt] = Bp[(ks * 4 + nt) * 64 + lane];
    const int ky  = ks >> 1;
    const int kx0 = ((ks & 1) << 3) + (quad << 1);
#pragma unroll
    for (int i = 0; i < 4; ++i) {
      int base = (((py_[i] + ky) * 48) + pxh_[i] + lc + kx0) << 2;  // ushort idx, 8B-aligned
      union { unsigned long long q[2]; v8s v; } u;
      u.q[0] = *(const unsigned long long*)(patchA + base);
      u.q[1] = *(const unsigned long long*)(patchA + base + 4);
#pragma unroll
      for (int nt = 0; nt < 4; ++nt)
        acc[i][nt] = __builtin_amdgcn_mfma_f32_16x16x32_bf16(u.v, Bf[nt], acc[i][nt], 0, 0, 0);
    }
  }

  // epilogue: +b1, ReLU, h1 -> LDS (C/D layout: col=lane&15 -> oc, row=quad*4+reg -> m)
  float b1v[4];
#pragma unroll
  for (int nt = 0; nt < 4; ++nt) b1v[nt] = (wf + B1F_OFF)[nt * 16 + lc];
#pragma unroll
  for (int i = 0; i < 4; ++i) {
#pragma unroll
    for (int nt = 0; nt < 4; ++nt) {
#pragma unroll
      for (int r = 0; r < 4; ++r) {
        int row = (quad << 2) + r;
        int pix = py_[i] * 32 + pxh_[i] + row;
        float vv = fmaxf(acc[i][nt][r] + b1v[nt], 0.f);
        h1[pix * 66 + nt * 16 + lc] = f2us(vv);
      }
    }
  }
  __syncthreads();

  // conv2 (1x1, 64->32) per pixel, VALU
  float acc2[32];
  const float* __restrict__ b2f = wf + B2F_OFF;
#pragma unroll
  for (int k = 0; k < 32; ++k) acc2[k] = b2f[k];
  const ushort_t* hp = h1 + tid * 66;
  const float* __restrict__ w2t = wf + W2T_OFF;
  for (int jj = 0; jj < 32; ++jj) {
    unsigned int w = *(const unsigned int*)(hp + jj * 2);
    float a0 = __uint_as_float(w << 16);
    float a1 = __uint_as_float(w & 0xffff0000u);
    const float* wa = w2t + (jj * 2) * 32;
    const float* wb = wa + 32;
#pragma unroll
    for (int k = 0; k < 32; ++k)
      acc2[k] = fmaf(a0, wa[k], fmaf(a1, wb[k], acc2[k]));
  }
  int px2 = tid & 31, py2 = tid >> 5;
  int gy = y0 + py2, gx = x0 + px2;
#pragma unroll
  for (int k = 0; k < 32; ++k)
    h2[((b * 32 + k) * 256 + gy) * 256 + gx] = f2us(fmaxf(acc2[k], 0.f));
}

// ---------------- K3: conv5x5(32->4), bf16 LDS patch, 2 px/thread ----------
// tile 32x16 pixels, grid (8,16,16)
__global__ __launch_bounds__(256) void k_conv3(
    const ushort_t* __restrict__ h2, const float* __restrict__ wf,
    void* __restrict__ out, const int* __restrict__ flag) {
  __shared__ ushort_t patch[32 * 20 * 36];   // [ic][y][x] bf16, 46080 B
  const int b  = blockIdx.z;
  const int x0 = blockIdx.x * 32, y0 = blockIdx.y * 16;
  const int tid = threadIdx.x;

  for (int e = tid; e < 32 * 20 * 36; e += 256) {
    int ic = e / 720, r = e % 720, yy = r / 36, xx = r % 36;
    int gy = y0 + yy - 2, gx = x0 + xx - 2;
    ushort_t v = 0;
    if (gy >= 0 && gy < 256 && gx >= 0 && gx < 256)
      v = h2[((b * 32 + ic) * 256 + gy) * 256 + gx];
    patch[e] = v;
  }
  __syncthreads();

  const int tx2 = tid & 15, ty = tid >> 4;
  const int px0 = tx2 * 2;
  const float* __restrict__ w3t = wf + W3T_OFF;
  const float* __restrict__ b3f = wf + B3F_OFF;

  float a0[4], a1[4];
#pragma unroll
  for (int oc = 0; oc < 4; ++oc) { a0[oc] = b3f[oc]; a1[oc] = b3f[oc]; }

  for (int ic = 0; ic < 32; ++ic) {
#pragma unroll
    for (int ky = 0; ky < 5; ++ky) {
      const ushort_t* rp = patch + ic * 720 + (ty + ky) * 36 + px0;
      unsigned int u0 = *(const unsigned int*)rp;
      unsigned int u1 = *(const unsigned int*)(rp + 2);
      unsigned int u2 = *(const unsigned int*)(rp + 4);
      float v[6];
      v[0] = __uint_as_float(u0 << 16); v[1] = __uint_as_float(u0 & 0xffff0000u);
      v[2] = __uint_as_float(u1 << 16); v[3] = __uint_as_float(u1 & 0xffff0000u);
      v[4] = __uint_as_float(u2 << 16); v[5] = __uint_as_float(u2 & 0xffff0000u);
#pragma unroll
      for (int kx = 0; kx < 5; ++kx) {
        float4 w = *(const float4*)(w3t + ((ic * 5 + ky) * 5 + kx) * 4);
        a0[0] = fmaf(v[kx], w.x, a0[0]); a0[1] = fmaf(v[kx], w.y, a0[1]);
        a0[2] = fmaf(v[kx], w.z, a0[2]); a0[3] = fmaf(v[kx], w.w, a0[3]);
        a1[0] = fmaf(v[kx + 1], w.x, a1[0]); a1[1] = fmaf(v[kx + 1], w.y, a1[1]);
        a1[2] = fmaf(v[kx + 1], w.z, a1[2]); a1[3] = fmaf(v[kx + 1], w.w, a1[3]);
      }
    }
  }

  int gy = y0 + ty, gx0 = x0 + px0;
  int base = (((b * 256 + gy) * 256 + gx0) << 2);
  if (flag[0]) {
    ushort_t* o = (ushort_t*)out + base;
#pragma unroll
    for (int oc = 0; oc < 4; ++oc) { o[oc] = f2us(a0[oc]); o[4 + oc] = f2us(a1[oc]); }
  } else {
    float* o = (float*)out + base;
    *(float4*)o       = make_float4(a0[0], a0[1], a0[2], a0[3]);
    *(float4*)(o + 4) = make_float4(a1[0], a1[1], a1[2], a1[3]);
  }
}

// ---------------------------------------------------------------------------
extern "C" void kernel_launch(void* const* d_in, const int* in_sizes, int n_in,
                              void* d_out, int out_size, void* d_ws, size_t ws_size,
                              hipStream_t stream) {
  const void* x  = d_in[0];
  const void* w1 = d_in[1];
  const void* b1 = d_in[2];
  const void* w2 = d_in[3];
  const void* b2 = d_in[4];
  const void* w3 = d_in[5];
  const void* b3 = d_in[6];

  float* wf = (float*)d_ws;
  ushort_t* pack1 = (ushort_t*)d_ws;
  int* flag = (int*)(wf + FLAG_OFF);
  float* up = wf + UP_OFF;
  ushort_t* h2 = (ushort_t*)(wf + H2_OFF_F);

  k_probe<<<1, 256, 0, stream>>>((const unsigned short*)x, flag);
  k_cvt<<<(PACK1_USHORTS + 5348 + 255) / 256, 256, 0, stream>>>(
      w1, b1, w2, b2, w3, b3, pack1, wf, flag);
  k_upscale<<<UP_ELEMS / 4 / 256, 256, 0, stream>>>(x, up, flag);
  k_conv12<<<dim3(8, 32, 16), 256, 0, stream>>>(up, pack1, wf, h2);
  k_conv3<<<dim3(8, 16, 16), 256, 0, stream>>>(h2, wf, d_out, flag);
}

// Round 4
// 180.035 us; speedup vs baseline: 3.9301x; 1.8739x over previous
//
#include <hip/hip_runtime.h>
#include <hip/hip_bf16.h>

typedef unsigned short ushort_t;
typedef __attribute__((ext_vector_type(8))) short v8s;   // 8 bf16 = 4 VGPR (MFMA A/B)
typedef __attribute__((ext_vector_type(4))) float v4f;   // MFMA C/D

// ---------------------------------------------------------------------------
// ws layout (ushort indices unless noted):
//   pack1 [0, 22528)        conv1 B-frags, dense K: [ks 11][nt 4][lane 64][8]
//   pack2 [22528, 26624)    conv2 B-frags hi/lo: [part 2][ks 2][nt 2][lane 64][8]
//   pack3 [26624, 67584)    conv3 B-frags hi/lo: [part 2][ks 40][lane 64][8]
//   floats at us 67584 (float idx 33792):
#define B1F_F   33792      // 64
#define B2F_F   33856      // 32
#define B3F_F   33888      // 4
#define WTAB_F  33892      // 32 (8 phases x 4 taps)
#define FLAG_I  33924      // int index (1 = bf16 inputs, 0 = fp32)
#define PK1_US  0
#define PK2_US  22528
#define PK3_US  26624
#define UP_US   69632      // bf16 NHWC [16][256][256][4]  (4M us = 8 MB)
#define H2_US   4263936    // bf16 NHWC [16][256][256][32] (32M us = 64 MB)
#define CVT_TOTAL (22528 + 4096 + 40960 + 132)
// ---------------------------------------------------------------------------

__device__ __forceinline__ ushort_t f2us(float v) {
  __hip_bfloat16 h = __float2bfloat16(v);
  return *reinterpret_cast<ushort_t*>(&h);
}
__device__ __forceinline__ float us2f(unsigned int u) { return __uint_as_float(u << 16); }

__device__ __forceinline__ float load_in(const void* p, int i, int isbf16) {
  if (isbf16) return us2f(((const unsigned short*)p)[i]);
  return ((const float*)p)[i];
}
__device__ __forceinline__ float4 load_in4(const void* p, int i4, int isbf16) {
  if (isbf16) {
    unsigned long long q = *(const unsigned long long*)((const unsigned short*)p + i4);
    return make_float4(us2f((unsigned int)(q & 0xffff)),
                       us2f((unsigned int)((q >> 16) & 0xffff)),
                       us2f((unsigned int)((q >> 32) & 0xffff)),
                       us2f((unsigned int)((q >> 48) & 0xffff)));
  }
  return *(const float4*)((const float*)p + i4);
}

__device__ __forceinline__ float cubicw(float d) {
  const float Ac = -0.75f;
  d = fabsf(d);
  float d2 = d * d, d3 = d2 * d;
  if (d <= 1.f) return (Ac + 2.f) * d3 - (Ac + 3.f) * d2 + 1.f;
  if (d < 2.f)  return Ac * d3 - 5.f * Ac * d2 + 8.f * Ac * d - 4.f * Ac;
  return 0.f;
}

// ---------------- K_probe: detect input dtype ------------------------------
__global__ __launch_bounds__(256) void k_probe(const unsigned short* __restrict__ xr,
                                               int* __restrict__ flag) {
  __shared__ int s[256];
  int tid = threadIdx.x;
  int cnt = 0;
  for (int i = tid; i < 512; i += 256) {
    unsigned short h = xr[2 * i];
    int e = (h >> 7) & 0xFF;
    if (e >= 110 && e <= 135) cnt++;
  }
  s[tid] = cnt;
  __syncthreads();
  if (tid == 0) {
    int t = 0;
    for (int i = 0; i < 256; i++) t += s[i];
    flag[0] = (t >= 256) ? 1 : 0;
  }
}

// ---------------- K_cvt: build weight packs + tables -----------------------
__global__ __launch_bounds__(256) void k_cvt(
    const void* __restrict__ w1, const void* __restrict__ b1,
    const void* __restrict__ w2, const void* __restrict__ b2,
    const void* __restrict__ w3, const void* __restrict__ b3,
    ushort_t* __restrict__ wsus, float* __restrict__ wsf,
    const int* __restrict__ flag) {
  int i = blockIdx.x * 256 + threadIdx.x;
  if (i >= CVT_TOTAL) return;
  const int f = flag[0];
  if (i < 22528) {
    // pack1 dense: k = ks*32+quad*8+j; k<324: tap=k>>2 (ky=tap/9,kx=tap%9), ic=k&3
    int j  = i & 7;
    int l  = (i >> 3) & 63;
    int nt = (i >> 9) & 3;
    int ks = i >> 11;
    int k  = ks * 32 + ((l >> 4) & 3) * 8 + j;
    int oc = nt * 16 + (l & 15);
    float v = 0.f;
    if (k < 324) {
      int tap = k >> 2, ic = k & 3;
      int ky = tap / 9, kx = tap - ky * 9;
      v = load_in(w1, ((oc * 4 + ic) * 9 + ky) * 9 + kx, f);
    }
    wsus[PK1_US + i] = f2us(v);
    return;
  }
  if (i < 26624) {
    // pack2 hi/lo: [part][ks][nt][lane][8]
    int t = i - 22528;
    int j  = t & 7;
    int l  = (t >> 3) & 63;
    int nt = (t >> 9) & 1;
    int ks = (t >> 10) & 1;
    int part = t >> 11;
    int oc1 = ks * 32 + ((l >> 4) & 3) * 8 + j;
    int oc2 = nt * 16 + (l & 15);
    float w = load_in(w2, oc2 * 64 + oc1, f);
    float hi = us2f(f2us(w));
    wsus[PK2_US + t] = part ? f2us(w - hi) : f2us(w);
    return;
  }
  if (i < 67584) {
    // pack3 hi/lo: [part][ks 40][lane][8]; k=ky*256+j*32+ic; n=dx*4+oc
    int t = i - 26624;
    int part = t / 20480;
    int r = t - part * 20480;
    int j8 = r & 7;
    int l  = (r >> 3) & 63;
    int ks = r >> 9;
    int k  = ks * 32 + ((l >> 4) & 3) * 8 + j8;
    int n  = l & 15;
    int ky = k >> 8, jj = (k >> 5) & 7, ic = k & 31;
    int dx = n >> 2, oc = n & 3;
    int kx = jj - dx;
    float w = 0.f;
    if (kx >= 0 && kx <= 4)
      w = load_in(w3, ((oc * 32 + ic) * 5 + ky) * 5 + kx, f);
    float hi = us2f(f2us(w));
    wsus[PK3_US + t] = part ? f2us(w - hi) : f2us(w);
    return;
  }
  int t = i - 67584;
  if (t < 64) { wsf[B1F_F + t] = load_in(b1, t, f); return; }
  if (t < 96) { wsf[B2F_F + (t - 64)] = load_in(b2, t - 64, f); return; }
  if (t < 100) { wsf[B3F_F + (t - 96)] = load_in(b3, t - 96, f); return; }
  if (t < 132) {
    int p = (t - 100) >> 2, a = (t - 100) & 3;
    float frac = (p + 0.5f) * 0.125f - 0.5f;
    float fl = floorf(frac);
    float tt = frac - fl;
    wsf[WTAB_F + (t - 100)] = cubicw(tt - (float)(a - 1));
  }
}

// ---------------- K1: bicubic x8 upscale -> bf16 NHWC ----------------------
__global__ __launch_bounds__(256) void k_upscale(
    const void* __restrict__ x, ushort_t* __restrict__ up,
    const float* __restrict__ wsf, const int* __restrict__ flag) {
  const int f = flag[0];
  int n = blockIdx.x * 256 + threadIdx.x;
  int xo = n & 255, yo = (n >> 8) & 255, b = n >> 16;
  int px = xo & 7, py = yo & 7;
  const float* wt = wsf + WTAB_F;
  float4 wx = *(const float4*)(wt + px * 4);
  float4 wy = *(const float4*)(wt + py * 4);
  float wya[4] = {wy.x, wy.y, wy.z, wy.w};
  int bx = (xo >> 3) + ((px >= 4) ? 0 : -1);
  int by = (yo >> 3) + ((py >= 4) ? 0 : -1);
  int ix0 = min(max(bx - 1, 0), 31), ix1 = min(max(bx, 0), 31);
  int ix2 = min(max(bx + 1, 0), 31), ix3 = min(max(bx + 2, 0), 31);
  float ax = 0.f, ay = 0.f, az = 0.f, aw = 0.f;
#pragma unroll
  for (int a = 0; a < 4; a++) {
    int iy = min(max(by + a - 1, 0), 31);
    int rowb = (b * 32 + iy) * 32;
    float4 p0 = load_in4(x, (rowb + ix0) * 4, f);
    float4 p1 = load_in4(x, (rowb + ix1) * 4, f);
    float4 p2 = load_in4(x, (rowb + ix2) * 4, f);
    float4 p3 = load_in4(x, (rowb + ix3) * 4, f);
    float rx = wx.x * p0.x + wx.y * p1.x + wx.z * p2.x + wx.w * p3.x;
    float ry = wx.x * p0.y + wx.y * p1.y + wx.z * p2.y + wx.w * p3.y;
    float rz = wx.x * p0.z + wx.y * p1.z + wx.z * p2.z + wx.w * p3.z;
    float rw = wx.x * p0.w + wx.y * p1.w + wx.z * p2.w + wx.w * p3.w;
    ax = fmaf(wya[a], rx, ax); ay = fmaf(wya[a], ry, ay);
    az = fmaf(wya[a], rz, az); aw = fmaf(wya[a], rw, aw);
  }
  unsigned long long q =
      (unsigned long long)f2us(ax) |
      ((unsigned long long)f2us(ay) << 16) |
      ((unsigned long long)f2us(az) << 32) |
      ((unsigned long long)f2us(aw) << 48);
  *(unsigned long long*)(up + n * 4) = q;
}

// ---------------- K2: MFMA conv9x9(4->64)+ReLU -> MFMA conv1x1(64->32)+ReLU
// tile 32x8 px, grid (8,32,16), 256 thr = 4 waves; wave owns 4 mtiles (its own px).
__global__ __launch_bounds__(256) void k_conv12(
    const ushort_t* __restrict__ up, const ushort_t* __restrict__ wsus,
    const float* __restrict__ wsf, ushort_t* __restrict__ h2) {
  __shared__ __align__(16) ushort_t patchA[16 * 48 * 4];  // [y][x][4ic] 12288 B
  __shared__ __align__(16) ushort_t h1[256 * 72];         // [pix][72] 36864 B
  const int b  = blockIdx.z;
  const int x0 = blockIdx.x * 32, y0 = blockIdx.y * 8;
  const int tid = threadIdx.x;

  // stage 16x48 positions from bf16 NHWC up (zero pad)
#pragma unroll
  for (int i = 0; i < 3; ++i) {
    int e = tid + i * 256;                  // 0..767
    int yy = e / 48, xx = e % 48;
    int gy = y0 + yy - 4, gx = x0 + xx - 4;
    unsigned long long q = 0ull;
    if (gy >= 0 && gy < 256 && gx >= 0 && gx < 256)
      q = *(const unsigned long long*)(up + (((b * 256 + gy) * 256 + gx) << 2));
    *(unsigned long long*)(patchA + e * 4) = q;
  }
  __syncthreads();

  const int lane = tid & 63, wave = tid >> 6;
  const int quad = lane >> 4, lc = lane & 15;
  int base_m[4], pix0_[4];
#pragma unroll
  for (int i = 0; i < 4; ++i) {
    int mt = wave * 4 + i;
    int py = mt >> 1, pxh = (mt & 1) << 4;
    base_m[i] = (py * 48 + pxh + lc) << 2;   // ushort idx of (py, pxh+lc, ic0)
    pix0_[i] = py * 32 + pxh;
  }
  v4f acc[4][4];
#pragma unroll
  for (int i = 0; i < 4; ++i)
#pragma unroll
    for (int nt = 0; nt < 4; ++nt) acc[i][nt] = (v4f){0.f, 0.f, 0.f, 0.f};

  const v8s* __restrict__ Bp = (const v8s*)(wsus + PK1_US);
  for (int ks = 0; ks < 11; ++ks) {
    v8s Bf[4];
#pragma unroll
    for (int nt = 0; nt < 4; ++nt) Bf[nt] = Bp[(ks * 4 + nt) * 64 + lane];
    int tap0 = ks * 8 + quad * 2;
    int tap1 = min(tap0 + 1, 80);
    tap0 = min(tap0, 80);
    int ky0 = tap0 / 9, kx0 = tap0 - ky0 * 9;
    int ky1 = tap1 / 9, kx1 = tap1 - ky1 * 9;
    int off0 = (ky0 * 48 + kx0) << 2;
    int off1 = (ky1 * 48 + kx1) << 2;
#pragma unroll
    for (int i = 0; i < 4; ++i) {
      union { unsigned long long q[2]; v8s v; } u;
      u.q[0] = *(const unsigned long long*)(patchA + base_m[i] + off0);
      u.q[1] = *(const unsigned long long*)(patchA + base_m[i] + off1);
#pragma unroll
      for (int nt = 0; nt < 4; ++nt)
        acc[i][nt] = __builtin_amdgcn_mfma_f32_16x16x32_bf16(u.v, Bf[nt], acc[i][nt], 0, 0, 0);
    }
  }

  // epilogue1: +b1, ReLU, h1 -> LDS rows of 72 (16B-aligned, bank-spread)
  float b1v[4];
#pragma unroll
  for (int nt = 0; nt < 4; ++nt) b1v[nt] = (wsf + B1F_F)[nt * 16 + lc];
#pragma unroll
  for (int i = 0; i < 4; ++i) {
#pragma unroll
    for (int nt = 0; nt < 4; ++nt) {
#pragma unroll
      for (int r = 0; r < 4; ++r) {
        int pix = pix0_[i] + (quad << 2) + r;
        float vv = fmaxf(acc[i][nt][r] + b1v[nt], 0.f);
        h1[pix * 72 + nt * 16 + lc] = f2us(vv);
      }
    }
  }
  // no barrier needed: each wave's conv2 pixels == its own conv1 pixels

  // conv2 MFMA (K=64 -> 2 ksteps, N=32 -> 2 ntiles, hi/lo weights)
  v4f acc2[4][2];
#pragma unroll
  for (int i = 0; i < 4; ++i) { acc2[i][0] = (v4f){0,0,0,0}; acc2[i][1] = (v4f){0,0,0,0}; }
  const v8s* __restrict__ Bp2 = (const v8s*)(wsus + PK2_US);
#pragma unroll
  for (int ks = 0; ks < 2; ++ks) {
    v8s af[4];
#pragma unroll
    for (int i = 0; i < 4; ++i)
      af[i] = *(const v8s*)(h1 + (pix0_[i] + lc) * 72 + ks * 32 + quad * 8);
#pragma unroll
    for (int part = 0; part < 2; ++part) {
#pragma unroll
      for (int nt = 0; nt < 2; ++nt) {
        v8s Bf = Bp2[((part * 2 + ks) * 2 + nt) * 64 + lane];
#pragma unroll
        for (int i = 0; i < 4; ++i)
          acc2[i][nt] = __builtin_amdgcn_mfma_f32_16x16x32_bf16(af[i], Bf, acc2[i][nt], 0, 0, 0);
      }
    }
  }

  // epilogue2: +b2, ReLU, store h2 NHWC bf16 (scatter 2B, 32B segments)
  float b2v[2];
  b2v[0] = (wsf + B2F_F)[lc];
  b2v[1] = (wsf + B2F_F)[16 + lc];
#pragma unroll
  for (int i = 0; i < 4; ++i) {
#pragma unroll
    for (int nt = 0; nt < 2; ++nt) {
#pragma unroll
      for (int r = 0; r < 4; ++r) {
        int pix = pix0_[i] + (quad << 2) + r;
        int gy = y0 + (pix >> 5), gx = x0 + (pix & 31);
        float vv = fmaxf(acc2[i][nt][r] + b2v[nt], 0.f);
        h2[(((b * 256 + gy) * 256 + gx) << 5) + nt * 16 + lc] = f2us(vv);
      }
    }
  }
}

// ---------------- K3: MFMA conv5x5(32->4) via dx-in-N trick ----------------
// n=(dx 0..3, oc 0..3); k=(ky 0..4, j=dx+kx 0..7, ic 0..31), K=1280, 40 ksteps.
// tile 32x(x) x 16(y) px, grid (8,16,16); M=128 (8 q-tiles), wave owns 2 q.
__global__ __launch_bounds__(256) void k_conv3(
    const ushort_t* __restrict__ h2, const ushort_t* __restrict__ wsus,
    const float* __restrict__ wsf, void* __restrict__ out,
    const int* __restrict__ flag) {
  __shared__ __align__(16) ushort_t patch[20 * 1160];  // [y 20][x 36][ic 32] + 8 pad/row
  const int b  = blockIdx.z;
  const int x0 = blockIdx.x * 32, y0 = blockIdx.y * 16;
  const int tid = threadIdx.x;

  for (int e = tid; e < 720; e += 256) {
    int yy = e / 36, xx = e - yy * 36;
    int gy = y0 + yy - 2, gx = x0 + xx - 2;
    ushort_t* dst = patch + yy * 1160 + xx * 32;
    if (gy >= 0 && gy < 256 && gx >= 0 && gx < 256) {
      const ushort_t* src = h2 + (((b * 256 + gy) * 256 + gx) << 5);
#pragma unroll
      for (int c = 0; c < 4; ++c)
        *(float4*)(dst + c * 8) = *(const float4*)(src + c * 8);
    } else {
      float4 z = make_float4(0.f, 0.f, 0.f, 0.f);
#pragma unroll
      for (int c = 0; c < 4; ++c) *(float4*)(dst + c * 8) = z;
    }
  }
  __syncthreads();

  const int lane = tid & 63, wave = tid >> 6;
  const int quad = lane >> 4, lc = lane & 15;
  v4f acc[2];
  acc[0] = (v4f){0.f, 0.f, 0.f, 0.f};
  acc[1] = (v4f){0.f, 0.f, 0.f, 0.f};
  const v8s* __restrict__ Bp3 = (const v8s*)(wsus + PK3_US);

  for (int ks = 0; ks < 40; ++ks) {
    v8s Bh = Bp3[ks * 64 + lane];
    v8s Bl = Bp3[(40 + ks) * 64 + lane];
    int ky = ks >> 3, j = ks & 7;
    int rowoff = (lc + ky) * 1160 + j * 32 + quad * 8;
#pragma unroll
    for (int i = 0; i < 2; ++i) {
      int q = wave * 2 + i;
      v8s Af = *(const v8s*)(patch + rowoff + q * 128);
      acc[i] = __builtin_amdgcn_mfma_f32_16x16x32_bf16(Af, Bh, acc[i], 0, 0, 0);
      acc[i] = __builtin_amdgcn_mfma_f32_16x16x32_bf16(Af, Bl, acc[i], 0, 0, 0);
    }
  }

  // epilogue: C/D row=quad*4+r -> y_local, col=lc -> (dx=lc>>2, oc=lc&3)
  float b3v = (wsf + B3F_F)[lc & 3];
  const int fl = flag[0];
#pragma unroll
  for (int i = 0; i < 2; ++i) {
    int q = wave * 2 + i;
#pragma unroll
    for (int r = 0; r < 4; ++r) {
      int gy = y0 + (quad << 2) + r;
      int gx = x0 + (q << 2) + (lc >> 2);
      int idx = (((b * 256 + gy) * 256 + gx) << 2) + (lc & 3);
      float vv = acc[i][r] + b3v;
      if (fl) ((ushort_t*)out)[idx] = f2us(vv);
      else    ((float*)out)[idx] = vv;
    }
  }
}

// ---------------------------------------------------------------------------
extern "C" void kernel_launch(void* const* d_in, const int* in_sizes, int n_in,
                              void* d_out, int out_size, void* d_ws, size_t ws_size,
                              hipStream_t stream) {
  const void* x  = d_in[0];
  const void* w1 = d_in[1];
  const void* b1 = d_in[2];
  const void* w2 = d_in[3];
  const void* b2 = d_in[4];
  const void* w3 = d_in[5];
  const void* b3 = d_in[6];

  ushort_t* wsus = (ushort_t*)d_ws;
  float* wsf = (float*)d_ws;
  int* flag = (int*)((float*)d_ws + FLAG_I);
  ushort_t* up = wsus + UP_US;
  ushort_t* h2 = wsus + H2_US;

  k_probe<<<1, 256, 0, stream>>>((const unsigned short*)x, flag);
  k_cvt<<<(CVT_TOTAL + 255) / 256, 256, 0, stream>>>(w1, b1, w2, b2, w3, b3, wsus, wsf, flag);
  k_upscale<<<4096, 256, 0, stream>>>(x, up, wsf, flag);
  k_conv12<<<dim3(8, 32, 16), 256, 0, stream>>>(up, wsus, wsf, h2);
  k_conv3<<<dim3(8, 16, 16), 256, 0, stream>>>(h2, wsus, wsf, d_out, flag);
}

// Round 5
// 170.982 us; speedup vs baseline: 4.1382x; 1.0529x over previous
//
#include <hip/hip_runtime.h>
#include <hip/hip_bf16.h>

typedef unsigned short ushort_t;
typedef __attribute__((ext_vector_type(8))) short v8s;   // 8 bf16 = 4 VGPR (MFMA A/B)
typedef __attribute__((ext_vector_type(4))) float v4f;   // MFMA C/D

// ---------------------------------------------------------------------------
// ws layout (ushort indices unless noted):
//   pack1 [0, 22528)        conv1 A-frags (weights), dense K: [ks 11][nt 4][lane 64][8]
//   pack2 [22528, 26624)    conv2 A-frags hi|lo-in-j: [nt 4][mt2 2][lane 64][8]
//   pack3 [26624, 47104)    conv3 B-frags (hi only): [ks 40][lane 64][8]
//   floats at us 47104 (float idx 23552):
#define B1F_F   23552      // 64
#define B2F_F   23616      // 32
#define B3F_F   23648      // 4
#define WTAB_F  23652      // 32 (8 phases x 4 taps)
#define FLAG_I  23684      // int (1 = bf16 inputs/outputs, 0 = fp32)
#define PK1_US  0
#define PK2_US  22528
#define PK3_US  26624
#define UP_US   48256      // bf16 NHWC [16][256][256][4]  (4M us = 8 MB)
#define H2_US   4242560    // bf16 NHWC [16][256][256][32] (32M us = 64 MB)
#define CVT_TOTAL (47104 + 132)
// ---------------------------------------------------------------------------

__device__ __forceinline__ ushort_t f2us(float v) {
  __hip_bfloat16 h = __float2bfloat16(v);
  return *reinterpret_cast<ushort_t*>(&h);
}
__device__ __forceinline__ float us2f(unsigned int u) { return __uint_as_float(u << 16); }

// RNE-pack two finite floats into two bf16 (lo = a, hi = b). 7 VALU, no NaN path.
__device__ __forceinline__ unsigned int bfpair(float a, float b) {
  unsigned int ua = __float_as_uint(a), ub = __float_as_uint(b);
  ua += 0x7fffu + ((ua >> 16) & 1u);
  ub += 0x7fffu + ((ub >> 16) & 1u);
  return (ua >> 16) | (ub & 0xffff0000u);
}

__device__ __forceinline__ float load_in(const void* p, int i, int isbf16) {
  if (isbf16) return us2f(((const unsigned short*)p)[i]);
  return ((const float*)p)[i];
}
__device__ __forceinline__ float4 load_in4(const void* p, int i4, int isbf16) {
  if (isbf16) {
    unsigned long long q = *(const unsigned long long*)((const unsigned short*)p + i4);
    return make_float4(us2f((unsigned int)(q & 0xffff)),
                       us2f((unsigned int)((q >> 16) & 0xffff)),
                       us2f((unsigned int)((q >> 32) & 0xffff)),
                       us2f((unsigned int)((q >> 48) & 0xffff)));
  }
  return *(const float4*)((const float*)p + i4);
}

__device__ __forceinline__ float cubicw(float d) {
  const float Ac = -0.75f;
  d = fabsf(d);
  float d2 = d * d, d3 = d2 * d;
  if (d <= 1.f) return (Ac + 2.f) * d3 - (Ac + 3.f) * d2 + 1.f;
  if (d < 2.f)  return Ac * d3 - 5.f * Ac * d2 + 8.f * Ac * d - 4.f * Ac;
  return 0.f;
}

// ---------------- K_cvt: inline dtype probe + build weight packs -----------
__global__ __launch_bounds__(256) void k_cvt(
    const void* __restrict__ x,
    const void* __restrict__ w1, const void* __restrict__ b1,
    const void* __restrict__ w2, const void* __restrict__ b2,
    const void* __restrict__ w3, const void* __restrict__ b3,
    ushort_t* __restrict__ wsus, float* __restrict__ wsf,
    int* __restrict__ flag) {
  __shared__ int scnt;
  const int tid = threadIdx.x;
  if (tid == 0) scnt = 0;
  __syncthreads();
  {
    const unsigned short* xr = (const unsigned short*)x;
    int c = 0;
    for (int s = tid; s < 512; s += 256) {
      unsigned short h = xr[2 * s];
      int e = (h >> 7) & 0xFF;
      if (e >= 110 && e <= 135) c++;
    }
    if (c) atomicAdd(&scnt, c);
  }
  __syncthreads();
  const int f = (scnt >= 256) ? 1 : 0;
  if (blockIdx.x == 0 && tid == 0) flag[0] = f;

  int i = blockIdx.x * 256 + tid;
  if (i >= CVT_TOTAL) return;
  if (i < 22528) {
    // pack1 dense: k = ks*32+quad*8+j; k<324: tap=k>>2 (ky=tap/9,kx=tap%9), ic=k&3
    // A-frag: lane&15 -> oc1 (m), quad*8+j -> k
    int j  = i & 7;
    int l  = (i >> 3) & 63;
    int nt = (i >> 9) & 3;
    int ks = i >> 11;
    int k  = ks * 32 + ((l >> 4) & 3) * 8 + j;
    int oc = nt * 16 + (l & 15);
    float v = 0.f;
    if (k < 324) {
      int tap = k >> 2, ic = k & 3;
      int ky = tap / 9, kx = tap - ky * 9;
      v = load_in(w1, ((oc * 4 + ic) * 9 + ky) * 9 + kx, f);
    }
    wsus[PK1_US + i] = f2us(v);
    return;
  }
  if (i < 26624) {
    // pack2: [nt][mt2][lane][8]; j<4 = hi(w2), j>=4 = lo residual; oc1=nt*16+quad*4+(j&3)
    int t = i - 22528;
    int j   = t & 7;
    int l   = (t >> 3) & 63;
    int mt2 = (t >> 9) & 1;
    int nt  = (t >> 10) & 3;
    int oc1 = nt * 16 + ((l >> 4) & 3) * 4 + (j & 3);
    int oc2 = mt2 * 16 + (l & 15);
    float w = load_in(w2, oc2 * 64 + oc1, f);
    float hi = us2f(f2us(w));
    wsus[PK2_US + t] = (j < 4) ? f2us(w) : f2us(w - hi);
    return;
  }
  if (i < 47104) {
    // pack3 (hi only): [ks 40][lane][8]; k=ky*256+jj*32+ic; n=dx*4+oc
    int t = i - 26624;
    int j8 = t & 7;
    int l  = (t >> 3) & 63;
    int ks = t >> 9;
    int k  = ks * 32 + ((l >> 4) & 3) * 8 + j8;
    int n  = l & 15;
    int ky = k >> 8, jj = (k >> 5) & 7, ic = k & 31;
    int dx = n >> 2, oc = n & 3;
    int kx = jj - dx;
    float w = 0.f;
    if (kx >= 0 && kx <= 4)
      w = load_in(w3, ((oc * 32 + ic) * 5 + ky) * 5 + kx, f);
    wsus[PK3_US + t] = f2us(w);
    return;
  }
  int t = i - 47104;
  if (t < 64) { wsf[B1F_F + t] = load_in(b1, t, f); return; }
  if (t < 96) { wsf[B2F_F + (t - 64)] = load_in(b2, t - 64, f); return; }
  if (t < 100) { wsf[B3F_F + (t - 96)] = load_in(b3, t - 96, f); return; }
  if (t < 132) {
    int p = (t - 100) >> 2, a = (t - 100) & 3;
    float frac = (p + 0.5f) * 0.125f - 0.5f;
    float fl = floorf(frac);
    float tt = frac - fl;
    wsf[WTAB_F + (t - 100)] = cubicw(tt - (float)(a - 1));
  }
}

// ---------------- K1: bicubic x8 upscale -> bf16 NHWC ----------------------
__global__ __launch_bounds__(256) void k_upscale(
    const void* __restrict__ x, ushort_t* __restrict__ up,
    const float* __restrict__ wsf, const int* __restrict__ flag) {
  const int f = flag[0];
  int n = blockIdx.x * 256 + threadIdx.x;
  int xo = n & 255, yo = (n >> 8) & 255, b = n >> 16;
  int px = xo & 7, py = yo & 7;
  const float* wt = wsf + WTAB_F;
  float4 wx = *(const float4*)(wt + px * 4);
  float4 wy = *(const float4*)(wt + py * 4);
  float wya[4] = {wy.x, wy.y, wy.z, wy.w};
  int bx = (xo >> 3) + ((px >= 4) ? 0 : -1);
  int by = (yo >> 3) + ((py >= 4) ? 0 : -1);
  int ix0 = min(max(bx - 1, 0), 31), ix1 = min(max(bx, 0), 31);
  int ix2 = min(max(bx + 1, 0), 31), ix3 = min(max(bx + 2, 0), 31);
  float ax = 0.f, ay = 0.f, az = 0.f, aw = 0.f;
#pragma unroll
  for (int a = 0; a < 4; a++) {
    int iy = min(max(by + a - 1, 0), 31);
    int rowb = (b * 32 + iy) * 32;
    float4 p0 = load_in4(x, (rowb + ix0) * 4, f);
    float4 p1 = load_in4(x, (rowb + ix1) * 4, f);
    float4 p2 = load_in4(x, (rowb + ix2) * 4, f);
    float4 p3 = load_in4(x, (rowb + ix3) * 4, f);
    float rx = wx.x * p0.x + wx.y * p1.x + wx.z * p2.x + wx.w * p3.x;
    float ry = wx.x * p0.y + wx.y * p1.y + wx.z * p2.y + wx.w * p3.y;
    float rz = wx.x * p0.z + wx.y * p1.z + wx.z * p2.z + wx.w * p3.z;
    float rw = wx.x * p0.w + wx.y * p1.w + wx.z * p2.w + wx.w * p3.w;
    ax = fmaf(wya[a], rx, ax); ay = fmaf(wya[a], ry, ay);
    az = fmaf(wya[a], rz, az); aw = fmaf(wya[a], rw, aw);
  }
  unsigned long long q =
      (unsigned long long)bfpair(ax, ay) |
      ((unsigned long long)bfpair(az, aw) << 32);
  *(unsigned long long*)(up + n * 4) = q;
}

// ---------------- K2: MFMA conv9x9(4->64)+ReLU -> MFMA conv1x1(64->32)+ReLU
// conv1 D = W1·patch (oc1 rows, pixel cols); D feeds conv2 directly as the
// B-operand (k=quad*4+r matches D row=quad*4+r).  conv2 = K=32 MFMA with
// hi|lo weight split folded into j (A = [hi|lo], B = values duplicated).
// tile 32x8 px, grid (8,32,16), 256 thr = 4 waves; wave owns 4 pixel-tiles.
__global__ __launch_bounds__(256) void k_conv12(
    const ushort_t* __restrict__ up, const ushort_t* __restrict__ wsus,
    const float* __restrict__ wsf, ushort_t* __restrict__ h2) {
  __shared__ __align__(16) ushort_t patchA[16 * 48 * 4];  // [y][x][4ic] 12288 B
  const int b  = blockIdx.z;
  const int x0 = blockIdx.x * 32, y0 = blockIdx.y * 8;
  const int tid = threadIdx.x;

  // stage 16x48 positions from bf16 NHWC up (zero pad)
#pragma unroll
  for (int i = 0; i < 3; ++i) {
    int e = tid + i * 256;                  // 0..767
    int yy = e / 48, xx = e % 48;
    int gy = y0 + yy - 4, gx = x0 + xx - 4;
    unsigned long long q = 0ull;
    if (gy >= 0 && gy < 256 && gx >= 0 && gx < 256)
      q = *(const unsigned long long*)(up + (((b * 256 + gy) * 256 + gx) << 2));
    *(unsigned long long*)(patchA + e * 4) = q;
  }
  __syncthreads();

  const int lane = tid & 63, wave = tid >> 6;
  const int quad = lane >> 4, lc = lane & 15;
  int base_m[4], pix0_[4];
#pragma unroll
  for (int i = 0; i < 4; ++i) {
    int mt = wave * 4 + i;
    int py = mt >> 1, pxh = (mt & 1) << 4;
    base_m[i] = (py * 48 + pxh + lc) << 2;   // ushort idx of (py, pxh+lc, ic0)
    pix0_[i] = py * 32 + pxh;
  }
  v4f acc[4][4];
#pragma unroll
  for (int i = 0; i < 4; ++i)
#pragma unroll
    for (int nt = 0; nt < 4; ++nt) acc[i][nt] = (v4f){0.f, 0.f, 0.f, 0.f};

  // preload conv2 A-frags (hi|lo packed): 8 frags x 4 VGPR
  v8s w2f[4][2];
#pragma unroll
  for (int nt = 0; nt < 4; ++nt)
#pragma unroll
    for (int mt2 = 0; mt2 < 2; ++mt2)
      w2f[nt][mt2] = ((const v8s*)(wsus + PK2_US))[(nt * 2 + mt2) * 64 + lane];

  const v8s* __restrict__ Ap1 = (const v8s*)(wsus + PK1_US);
  for (int ks = 0; ks < 11; ++ks) {
    v8s Af[4];
#pragma unroll
    for (int nt = 0; nt < 4; ++nt) Af[nt] = Ap1[(ks * 4 + nt) * 64 + lane];
    int tap0 = ks * 8 + quad * 2;
    int tap1 = min(tap0 + 1, 80);
    tap0 = min(tap0, 80);
    int ky0 = tap0 / 9, kx0 = tap0 - ky0 * 9;
    int ky1 = tap1 / 9, kx1 = tap1 - ky1 * 9;
    int off0 = (ky0 * 48 + kx0) << 2;
    int off1 = (ky1 * 48 + kx1) << 2;
#pragma unroll
    for (int i = 0; i < 4; ++i) {
      union { unsigned long long q[2]; v8s v; } u;
      u.q[0] = *(const unsigned long long*)(patchA + base_m[i] + off0);
      u.q[1] = *(const unsigned long long*)(patchA + base_m[i] + off1);
#pragma unroll
      for (int nt = 0; nt < 4; ++nt)
        acc[i][nt] = __builtin_amdgcn_mfma_f32_16x16x32_bf16(Af[nt], u.v, acc[i][nt], 0, 0, 0);
    }
  }

  // epilogue: +b1, ReLU, pack -> conv2 MFMA -> +b2, ReLU, packed h2 store
  float4 b1q[4];
#pragma unroll
  for (int nt = 0; nt < 4; ++nt)
    b1q[nt] = *(const float4*)(wsf + B1F_F + nt * 16 + quad * 4);
  float4 b2q[2];
#pragma unroll
  for (int mt2 = 0; mt2 < 2; ++mt2)
    b2q[mt2] = *(const float4*)(wsf + B2F_F + mt2 * 16 + quad * 4);

#pragma unroll
  for (int i = 0; i < 4; ++i) {
    v4f a2[2];
    a2[0] = (v4f){0.f, 0.f, 0.f, 0.f};
    a2[1] = (v4f){0.f, 0.f, 0.f, 0.f};
#pragma unroll
    for (int nt = 0; nt < 4; ++nt) {
      float r0 = fmaxf(acc[i][nt][0] + b1q[nt].x, 0.f);
      float r1 = fmaxf(acc[i][nt][1] + b1q[nt].y, 0.f);
      float r2 = fmaxf(acc[i][nt][2] + b1q[nt].z, 0.f);
      float r3 = fmaxf(acc[i][nt][3] + b1q[nt].w, 0.f);
      unsigned int u0 = bfpair(r0, r1), u1 = bfpair(r2, r3);
      union { unsigned int q[4]; v8s v; } bu;
      bu.q[0] = u0; bu.q[1] = u1; bu.q[2] = u0; bu.q[3] = u1;
#pragma unroll
      for (int mt2 = 0; mt2 < 2; ++mt2)
        a2[mt2] = __builtin_amdgcn_mfma_f32_16x16x32_bf16(w2f[nt][mt2], bu.v, a2[mt2], 0, 0, 0);
    }
    int pix = pix0_[i] + lc;
    int gy = y0 + (pix >> 5), gx = x0 + (pix & 31);
    ushort_t* dst = h2 + (((b * 256 + gy) * 256 + gx) << 5) + (quad << 2);
#pragma unroll
    for (int mt2 = 0; mt2 < 2; ++mt2) {
      float v0 = fmaxf(a2[mt2][0] + b2q[mt2].x, 0.f);
      float v1 = fmaxf(a2[mt2][1] + b2q[mt2].y, 0.f);
      float v2 = fmaxf(a2[mt2][2] + b2q[mt2].z, 0.f);
      float v3 = fmaxf(a2[mt2][3] + b2q[mt2].w, 0.f);
      unsigned long long q =
          (unsigned long long)bfpair(v0, v1) |
          ((unsigned long long)bfpair(v2, v3) << 32);
      *(unsigned long long*)(dst + mt2 * 16) = q;
    }
  }
}

// ---------------- K3: MFMA conv5x5(32->4) via dx-in-N trick ----------------
// n=(dx 0..3, oc 0..3); k=(ky 0..4, j=dx+kx 0..7, ic 0..31), K=1280, 40 ksteps.
// tile 32x16 px, grid (8,16,16); M=128 (8 q-tiles), wave owns 2 q.
__global__ __launch_bounds__(256) void k_conv3(
    const ushort_t* __restrict__ h2, const ushort_t* __restrict__ wsus,
    const float* __restrict__ wsf, void* __restrict__ out,
    const int* __restrict__ flag) {
  __shared__ __align__(16) ushort_t patch[20 * 1160];  // [y 20][x 36][ic 32] + 8 pad/row
  const int b  = blockIdx.z;
  const int x0 = blockIdx.x * 32, y0 = blockIdx.y * 16;
  const int tid = threadIdx.x;

  for (int e = tid; e < 720; e += 256) {
    int yy = e / 36, xx = e - yy * 36;
    int gy = y0 + yy - 2, gx = x0 + xx - 2;
    ushort_t* dst = patch + yy * 1160 + xx * 32;
    if (gy >= 0 && gy < 256 && gx >= 0 && gx < 256) {
      const ushort_t* src = h2 + (((b * 256 + gy) * 256 + gx) << 5);
#pragma unroll
      for (int c = 0; c < 4; ++c)
        *(float4*)(dst + c * 8) = *(const float4*)(src + c * 8);
    } else {
      float4 z = make_float4(0.f, 0.f, 0.f, 0.f);
#pragma unroll
      for (int c = 0; c < 4; ++c) *(float4*)(dst + c * 8) = z;
    }
  }
  __syncthreads();

  const int lane = tid & 63, wave = tid >> 6;
  const int quad = lane >> 4, lc = lane & 15;
  v4f acc[2];
  acc[0] = (v4f){0.f, 0.f, 0.f, 0.f};
  acc[1] = (v4f){0.f, 0.f, 0.f, 0.f};
  const v8s* __restrict__ Bp3 = (const v8s*)(wsus + PK3_US);

  for (int ks = 0; ks < 40; ++ks) {
    v8s Bh = Bp3[ks * 64 + lane];
    int ky = ks >> 3, j = ks & 7;
    int rowoff = (lc + ky) * 1160 + j * 32 + quad * 8;
#pragma unroll
    for (int i = 0; i < 2; ++i) {
      int q = wave * 2 + i;
      v8s Af = *(const v8s*)(patch + rowoff + q * 128);
      acc[i] = __builtin_amdgcn_mfma_f32_16x16x32_bf16(Af, Bh, acc[i], 0, 0, 0);
    }
  }

  // epilogue: C/D row=quad*4+r -> y_local, col=lc -> (dx=lc>>2, oc=lc&3)
  float b3v = (wsf + B3F_F)[lc & 3];
  const int fl = flag[0];
#pragma unroll
  for (int i = 0; i < 2; ++i) {
    int q = wave * 2 + i;
#pragma unroll
    for (int r = 0; r < 4; ++r) {
      int gy = y0 + (quad << 2) + r;
      int gx = x0 + (q << 2) + (lc >> 2);
      int idx = (((b * 256 + gy) * 256 + gx) << 2) + (lc & 3);
      float vv = acc[i][r] + b3v;
      if (fl) ((ushort_t*)out)[idx] = f2us(vv);
      else    ((float*)out)[idx] = vv;
    }
  }
}

// ---------------------------------------------------------------------------
extern "C" void kernel_launch(void* const* d_in, const int* in_sizes, int n_in,
                              void* d_out, int out_size, void* d_ws, size_t ws_size,
                              hipStream_t stream) {
  const void* x  = d_in[0];
  const void* w1 = d_in[1];
  const void* b1 = d_in[2];
  const void* w2 = d_in[3];
  const void* b2 = d_in[4];
  const void* w3 = d_in[5];
  const void* b3 = d_in[6];

  ushort_t* wsus = (ushort_t*)d_ws;
  float* wsf = (float*)d_ws;
  int* flag = (int*)((float*)d_ws + FLAG_I);
  ushort_t* up = wsus + UP_US;
  ushort_t* h2 = wsus + H2_US;

  k_cvt<<<(CVT_TOTAL + 255) / 256, 256, 0, stream>>>(x, w1, b1, w2, b2, w3, b3,
                                                     wsus, wsf, flag);
  k_upscale<<<4096, 256, 0, stream>>>(x, up, wsf, flag);
  k_conv12<<<dim3(8, 32, 16), 256, 0, stream>>>(up, wsus, wsf, h2);
  k_conv3<<<dim3(8, 16, 16), 256, 0, stream>>>(h2, wsus, wsf, d_out, flag);
}